// Round 3
// baseline (286.393 us; speedup 1.0000x reference)
//
#include <hip/hip_runtime.h>
#include <math.h>

#define NV 8
#define NC 14
#define NH 480
#define NW 640
#define HW (NH * NW)
#define NPIX (NV * HW)
#define OC 15
#define BLK 256
#define PPT 4                 // pixels per thread
#define PPB (BLK * PPT)       // 1024 pixels per block
#define BPV (HW / PPB)        // 300 blocks per view (exact)
#define NB  (NPIX / PPB)      // 2400 blocks

#define LOG2E 1.44269504088896340736f
#define LN2   0.69314718055994530942f

// ---- single-instruction HW math ----
__device__ __forceinline__ float fexp2_(float x) {
#if __has_builtin(__builtin_amdgcn_exp2f)
    return __builtin_amdgcn_exp2f(x);
#else
    return exp2f(x);
#endif
}
__device__ __forceinline__ float flog2_(float x) {
#if __has_builtin(__builtin_amdgcn_logf)
    return __builtin_amdgcn_logf(x);
#else
    return log2f(x);
#endif
}
__device__ __forceinline__ float frcp_(float x) {
#if __has_builtin(__builtin_amdgcn_rcpf)
    return __builtin_amdgcn_rcpf(x);
#else
    return 1.0f / x;
#endif
}
__device__ __forceinline__ float frsq_(float x) {
#if __has_builtin(__builtin_amdgcn_rsqf)
    return __builtin_amdgcn_rsqf(x);
#else
    return rsqrtf(x);
#endif
}

__device__ __forceinline__ float sigmoidf_(float x) {
    return frcp_(1.0f + fexp2_(-x * LOG2E));
}
__device__ __forceinline__ float softplusf_(float x) {
    return fmaxf(x, 0.0f) + LN2 * flog2_(1.0f + fexp2_(-fabsf(x) * LOG2E));
}

__global__ __launch_bounds__(BLK, 4) void DecoderSplatting_kernel(
    const float* __restrict__ raw,   // (1, V, C, H, W)
    const float* __restrict__ ext,   // (1, V, 4, 4)
    const float* __restrict__ intr,  // (1, V, 3, 3)
    float* __restrict__ out)         // (V, H, W, 15)
{
    const int tid = threadIdx.x;
    const int v = blockIdx.x / BPV;                       // uniform -> SGPR
    const int pin0 = (blockIdx.x - v * BPV) * PPB + tid * PPT;
    const int py  = pin0 / NW;                            // 4 px never cross a row (640%4==0)
    const int px0 = pin0 - py * NW;

    // ---- per-view constants (uniform -> s_load) ----
    const float* E = ext + v * 16;
    const float* K = intr + v * 9;
    const float a00 = K[0], a01 = K[1], a02 = K[2];
    const float a10 = K[3], a11 = K[4], a12 = K[5];
    const float a20 = K[6], a21 = K[7], a22 = K[8];
    const float c00 = a11 * a22 - a12 * a21;
    const float c01 = a12 * a20 - a10 * a22;
    const float c02 = a10 * a21 - a11 * a20;
    const float invdet = 1.0f / (a00 * c00 + a01 * c01 + a02 * c02);
    const float i00 = c00 * invdet;
    const float i01 = (a02 * a21 - a01 * a22) * invdet;
    const float i02 = (a01 * a12 - a02 * a11) * invdet;
    const float i10 = c01 * invdet;
    const float i11 = (a00 * a22 - a02 * a20) * invdet;
    const float i12 = (a02 * a10 - a00 * a12) * invdet;
    const float i20 = c02 * invdet;
    const float i21 = (a01 * a20 - a00 * a21) * invdet;
    const float i22 = (a00 * a11 - a01 * a10) * invdet;
    const float mult = (a00 + a11 - a01 - a10) / (a00 * a11 - a01 * a10);

    const float e0 = E[0],  e1 = E[1],  e2 = E[2],  e3 = E[3];
    const float e4 = E[4],  e5 = E[5],  e6 = E[6],  e7 = E[7];
    const float e8 = E[8],  e9 = E[9],  e10 = E[10], e11 = E[11];
    const float e12 = E[12], e13 = E[13], e14 = E[14], e15 = E[15];

    // ---- issue ALL 14 float4 plane loads up-front (14 KB in flight per wave) ----
    const float* base = raw + (size_t)v * NC * HW;
    float4 ch4[NC];
#pragma unroll
    for (int c = 0; c < NC; ++c)
        ch4[c] = *(const float4*)(base + (size_t)c * HW + pin0);

    float ob[PPT * OC];  // 60 floats, fully unrolled constant indices -> registers

#pragma unroll
    for (int p = 0; p < PPT; ++p) {
        float ch[NC];
#pragma unroll
        for (int c = 0; c < NC; ++c)
            ch[c] = (p == 0) ? ch4[c].x : (p == 1) ? ch4[c].y : (p == 2) ? ch4[c].z : ch4[c].w;

        // ---- ray direction ----
        const float cx = (float)(px0 + p) + sigmoidf_(ch[12]) - 0.5f;
        const float cy = (float)py + sigmoidf_(ch[13]) - 0.5f;
        float dx = i00 * cx + i01 * cy + i02;
        float dy = i10 * cx + i11 * cy + i12;
        float dz = i20 * cx + i21 * cy + i22;
        const float dinv = frsq_(dx * dx + dy * dy + dz * dz);
        dx *= dinv; dy *= dinv; dz *= dinv;

        // ---- depth + means (incl. homogeneous row) ----
        const float depth = frcp_(sigmoidf_(ch[3]) * 19.95f + 0.05f);
        const float m0 = e3  + (e0  * dx + e1  * dy + e2  * dz) * depth;
        const float m1 = e7  + (e4  * dx + e5  * dy + e6  * dz) * depth;
        const float m2 = e11 + (e8  * dx + e9  * dy + e10 * dz) * depth;
        const float m3 = e15 + (e12 * dx + e13 * dy + e14 * dz) * depth;

        // ---- rgb / opacity / scales ----
        const float r0 = softplusf_(ch[0]);
        const float r1 = softplusf_(ch[1]);
        const float r2 = softplusf_(ch[2]);
        const float op = sigmoidf_(ch[4]);
        const float s0 = softplusf_(ch[5]) * mult;
        const float s1 = softplusf_(ch[6]) * mult;
        const float s2 = softplusf_(ch[7]) * mult;

        // ---- rotation normalize (single rsq == ref's double normalize to ~1e-6) ----
        float qx = ch[8], qy = ch[9], qz = ch[10], qw = ch[11];
        const float qinv = frsq_(qx * qx + qy * qy + qz * qz + qw * qw);
        qx *= qinv; qy *= qinv; qz *= qinv; qw *= qinv;

        const float b00 = 1.0f - 2.0f * (qy * qy + qz * qz);
        const float b01 = 2.0f * (qx * qy - qz * qw);
        const float b02 = 2.0f * (qx * qz + qy * qw);
        const float b10 = 2.0f * (qx * qy + qz * qw);
        const float b11 = 1.0f - 2.0f * (qx * qx + qz * qz);
        const float b12 = 2.0f * (qy * qz - qx * qw);
        const float b20 = 2.0f * (qx * qz - qy * qw);
        const float b21 = 2.0f * (qy * qz + qx * qw);
        const float b22 = 1.0f - 2.0f * (qx * qx + qy * qy);

        const float M00 = e0 * b00 + e1 * b10 + e2 * b20;
        const float M01 = e0 * b01 + e1 * b11 + e2 * b21;
        const float M02 = e0 * b02 + e1 * b12 + e2 * b22;
        const float M10 = e4 * b00 + e5 * b10 + e6 * b20;
        const float M11 = e4 * b01 + e5 * b11 + e6 * b21;
        const float M12 = e4 * b02 + e5 * b12 + e6 * b22;
        const float M20 = e8 * b00 + e9 * b10 + e10 * b20;
        const float M21 = e8 * b01 + e9 * b11 + e10 * b21;
        const float M22 = e8 * b02 + e9 * b12 + e10 * b22;

        // mat -> quat (wxyz), first-occurrence argmax([M00,M11,M22,tr])
        const float tr = M00 + M11 + M22;
        int choice = 0;
        float best = M00;
        if (M11 > best) { best = M11; choice = 1; }
        if (M22 > best) { best = M22; choice = 2; }
        if (tr  > best) { best = tr;  choice = 3; }

        float w0, w1, w2, w3;
        if (choice == 0) {
            w0 = M21 - M12; w1 = 1.0f + M00 - M11 - M22; w2 = M01 + M10; w3 = M02 + M20;
        } else if (choice == 1) {
            w0 = M02 - M20; w1 = M01 + M10; w2 = 1.0f + M11 - M00 - M22; w3 = M12 + M21;
        } else if (choice == 2) {
            w0 = M10 - M01; w1 = M02 + M20; w2 = M12 + M21; w3 = 1.0f + M22 - M00 - M11;
        } else {
            w0 = 1.0f + tr; w1 = M21 - M12; w2 = M02 - M20; w3 = M10 - M01;
        }
        const float winv = frsq_(w0 * w0 + w1 * w1 + w2 * w2 + w3 * w3);

        float* o = ob + p * OC;
        o[0]  = m0;  o[1]  = m1;  o[2]  = m2;  o[3]  = m3;
        o[4]  = r0;  o[5]  = r1;  o[6]  = r2;
        o[7]  = op;
        o[8]  = s0;  o[9]  = s1;  o[10] = s2;
        o[11] = w0 * winv; o[12] = w1 * winv; o[13] = w2 * winv; o[14] = w3 * winv;
    }

    // ---- 15 contiguous float4 stores (60 floats/thread, 16B-aligned: 240B = 15*16) ----
    float4* o4 = (float4*)(out + (size_t)(v * HW + pin0) * OC);
#pragma unroll
    for (int j = 0; j < (PPT * OC) / 4; ++j)
        o4[j] = *(const float4*)(ob + 4 * j);
}

extern "C" void kernel_launch(void* const* d_in, const int* in_sizes, int n_in,
                              void* d_out, int out_size, void* d_ws, size_t ws_size,
                              hipStream_t stream) {
    const float* raw  = (const float*)d_in[0];
    const float* ext  = (const float*)d_in[1];
    const float* intr = (const float*)d_in[2];
    float* out = (float*)d_out;

    DecoderSplatting_kernel<<<dim3(NB), dim3(BLK), 0, stream>>>(raw, ext, intr, out);
}